// Round 10
// baseline (870.144 us; speedup 1.0000x reference)
//
#include <hip/hip_runtime.h>

// GraphSAGE fwd. R8->R9: register-direct split-bf16 MFMA GEMM (no LDS, no barriers);
// all GEMM operands pre-split into bf16 hi/lo pairs (W once via k_split; h/hn split
// in producing kernels' epilogues) so the K-loop has zero conversion VALU except
// the features GEMM (fp32 input). Numerics identical to R8 (same RNE hi/lo split,
// same 3-term MFMA, fp16 shadow for aggregation).
// ws layout (bytes):
//   h(f32, final only): 0 .. 51,200,000
//   h16   : 51,200,000  (25.6MB)   h_hi: 76,800,000   h_lo: 102,400,000
//   hn_h  : 128,000,000            hn_l: 153,600,000
//   deg   : 179,200,000  inv_deg: 179,600,000  row_start: 180,000,000
//   cursor: 180,400,016  csr_src: 180,800,016  bsums: 187,200,016  boffs: 187,200,272
//   W_in_h: 187,201,024  W_in_l: 187,332,096
//   W_sf_h: 187,463,168  W_sf_l: 187,528,704  W_ng_h: 187,594,240  W_ng_l: 187,659,776

#define N_NODES 100000
#define N_EDGES 1600000
#define IN_FEATS 512
#define HIDDEN 128
#define NEG_SLOPE 0.01f
#define SCAN_BLOCKS 49  // ceil(100000/2048)

#define N_RANGES 8
#define RANGE_SZ 12500
#define FILL_CHUNKS 256
#define FILL_CHUNK 6250

typedef __attribute__((ext_vector_type(8))) __bf16 bf16x8;
typedef __attribute__((ext_vector_type(4))) __bf16 bf16x4;
typedef __attribute__((ext_vector_type(4))) float f32x4;
typedef __attribute__((ext_vector_type(8))) _Float16 half8;

// ---------------- CSR build (XCD-local ranged scatter, R2) ----------------
__global__ __launch_bounds__(256) void k_degree(const int* __restrict__ dst,
                                                int* __restrict__ deg) {
  int r = blockIdx.x & 7;
  int c = blockIdx.x >> 3;
  int lo = r * RANGE_SZ, hi = lo + RANGE_SZ;
  int e0 = c * FILL_CHUNK;
  int e1 = e0 + FILL_CHUNK;
  if (e1 > N_EDGES) e1 = N_EDGES;
  for (int e = e0 + threadIdx.x; e < e1; e += 256) {
    int d = dst[e];
    if (d >= lo && d < hi) atomicAdd(&deg[d], 1);
  }
}

__device__ __forceinline__ int wave_incl_scan(int v) {
  #pragma unroll
  for (int d = 1; d < 64; d <<= 1) {
    int t = __shfl_up(v, d, 64);
    if ((threadIdx.x & 63) >= d) v += t;
  }
  return v;
}

__global__ __launch_bounds__(256) void k_scanA(const int* __restrict__ deg,
                                               int* __restrict__ out,
                                               int* __restrict__ bsums) {
  __shared__ int wsum[4];
  int base = blockIdx.x * 2048 + threadIdx.x * 8;
  int v[8];
  int s = 0;
  #pragma unroll
  for (int i = 0; i < 8; i++) {
    int idx = base + i;
    v[i] = (idx < N_NODES) ? deg[idx] : 0;
    s += v[i];
  }
  int incl = wave_incl_scan(s);
  int wid = threadIdx.x >> 6;
  if ((threadIdx.x & 63) == 63) wsum[wid] = incl;
  __syncthreads();
  int woff = 0;
  #pragma unroll
  for (int w = 0; w < 4; w++)
    if (w < wid) woff += wsum[w];
  int run = woff + incl - s;
  #pragma unroll
  for (int i = 0; i < 8; i++) {
    int idx = base + i;
    if (idx < N_NODES) out[idx] = run;
    run += v[i];
  }
  if (threadIdx.x == 255) bsums[blockIdx.x] = woff + incl;
}

__global__ __launch_bounds__(64) void k_scanB(const int* __restrict__ bsums,
                                              int* __restrict__ boffs) {
  int t = threadIdx.x;
  int v = (t < SCAN_BLOCKS) ? bsums[t] : 0;
  int incl = wave_incl_scan(v);
  if (t < SCAN_BLOCKS) boffs[t] = incl - v;
}

__global__ __launch_bounds__(256) void k_scanC(const int* __restrict__ deg,
                                               int* __restrict__ row_start,
                                               int* __restrict__ cursor,
                                               float* __restrict__ inv_deg,
                                               const int* __restrict__ boffs) {
  int b = boffs[blockIdx.x];
  int base = blockIdx.x * 2048 + threadIdx.x * 8;
  #pragma unroll
  for (int i = 0; i < 8; i++) {
    int idx = base + i;
    if (idx < N_NODES) {
      int rs = row_start[idx] + b;
      row_start[idx] = rs;
      cursor[idx] = rs;
      int d = deg[idx];
      inv_deg[idx] = 1.0f / (float)(d > 1 ? d : 1);
    }
  }
  if (blockIdx.x == 0 && threadIdx.x == 0) row_start[N_NODES] = N_EDGES;
}

__global__ __launch_bounds__(256) void k_fill(const int* __restrict__ src,
                                              const int* __restrict__ dst,
                                              int* __restrict__ cursor,
                                              int* __restrict__ csr_src) {
  int r = blockIdx.x & 7;
  int c = blockIdx.x >> 3;
  int lo = r * RANGE_SZ, hi = lo + RANGE_SZ;
  int e0 = c * FILL_CHUNK;
  int e1 = e0 + FILL_CHUNK;
  if (e1 > N_EDGES) e1 = N_EDGES;
  for (int e = e0 + threadIdx.x; e < e1; e += 256) {
    int d = dst[e];
    if (d >= lo && d < hi) {
      int p = atomicAdd(&cursor[d], 1);
      csr_src[p] = src[e];
    }
  }
}

// ---------------- fp32 -> bf16 hi/lo splitter (weights) ----------------
__global__ __launch_bounds__(256) void k_split(const float* __restrict__ in,
                                               __bf16* __restrict__ hi,
                                               __bf16* __restrict__ lo, int n) {
  int i = (blockIdx.x * 256 + threadIdx.x) * 4;
  if (i >= n) return;
  float4 v = *(const float4*)&in[i];
  float vv[4] = {v.x, v.y, v.z, v.w};
  bf16x4 h4, l4;
  #pragma unroll
  for (int j = 0; j < 4; j++) {
    __bf16 hh = (__bf16)vv[j];
    h4[j] = hh;
    l4[j] = (__bf16)(vv[j] - (float)hh);
  }
  *(bf16x4*)&hi[i] = h4;
  *(bf16x4*)&lo[i] = l4;
}

// ---------------- register-direct split-bf16 MFMA GEMM ----------------
// C[i][col] = sum_k A[i][k]*W[col][k] + bias[col]; virtual K = K1 then K2.
// BM=128, BN=128; 4 waves 2x2, each 64x64 via 4x4 frags of mfma_f32_16x16x32_bf16.
// No LDS: lane (lr,kg) loads its fragment bytes [k0+kg*8..+7] of its rows directly.
// A16: A operands are pre-split bf16 hi/lo. Else fp32, split in-loop (RNE).
// Requires K2==0 || K2==K1 (uniform lda).
template <int K1, int K2, bool RELU, bool A16, bool WF32, bool WSPLIT, bool WF16>
__global__ __launch_bounds__(256, 2) void k_gemm(
    const void* __restrict__ A1a, const void* __restrict__ A1b,
    const void* __restrict__ A2a, const void* __restrict__ A2b,
    const __bf16* __restrict__ W1h, const __bf16* __restrict__ W1l,
    const __bf16* __restrict__ W2h, const __bf16* __restrict__ W2l,
    const float* __restrict__ bias,
    float* __restrict__ Cf, __bf16* __restrict__ Ch, __bf16* __restrict__ Cl,
    _Float16* __restrict__ C16) {
  static_assert(K2 == 0 || K2 == K1, "uniform lda required");
  constexpr int BK = 32;
  constexpr int KT = (K1 + K2) / BK;
  const int tid = threadIdx.x;
  const int lane = tid & 63;
  const int wid = tid >> 6;
  const int wr = wid >> 1, wc = wid & 1;
  const int lr = lane & 15, kg = lane >> 4;
  const int r0 = blockIdx.x * 128;

  long abase[4];  // element offset of row start (clamped; garbage never stored)
  long bbase[4];
  #pragma unroll
  for (int m = 0; m < 4; m++) {
    int r = r0 + wr * 64 + m * 16 + lr;
    int rc = (r < N_NODES) ? r : (N_NODES - 1);
    abase[m] = (long)rc * K1;
    bbase[m] = (long)(wc * 64 + m * 16 + lr) * K1;
  }

  f32x4 acc[4][4];
  #pragma unroll
  for (int m = 0; m < 4; m++)
    #pragma unroll
    for (int n = 0; n < 4; n++) acc[m][n] = (f32x4){0.f, 0.f, 0.f, 0.f};

  float4 af[4][2];                      // staged raw A (fp32 path)
  bf16x8 sah[4], sal[4];                // staged A frags (bf16 path)
  bf16x8 sbh[4], sbl[4];                // staged B frags
  bf16x8 ah[4], al[4], bh[4], bl[4];    // current operands

  auto issue = [&](int kt) {
    const bool fst = (K2 == 0) || (kt * BK < K1);
    const int k0 = (fst ? kt * BK : kt * BK - K1) + kg * 8;
    if constexpr (A16) {
      const __bf16* Ah = (const __bf16*)(fst ? A1a : A2a);
      const __bf16* Al = (const __bf16*)(fst ? A1b : A2b);
      #pragma unroll
      for (int m = 0; m < 4; m++) {
        sah[m] = *(const bf16x8*)&Ah[abase[m] + k0];
        sal[m] = *(const bf16x8*)&Al[abase[m] + k0];
      }
    } else {
      const float* Af = (const float*)(fst ? A1a : A2a);
      #pragma unroll
      for (int m = 0; m < 4; m++) {
        af[m][0] = *(const float4*)&Af[abase[m] + k0];
        af[m][1] = *(const float4*)&Af[abase[m] + k0 + 4];
      }
    }
    const __bf16* Bh = fst ? W1h : W2h;
    const __bf16* Bl = fst ? W1l : W2l;
    #pragma unroll
    for (int n = 0; n < 4; n++) {
      sbh[n] = *(const bf16x8*)&Bh[bbase[n] + k0];
      sbl[n] = *(const bf16x8*)&Bl[bbase[n] + k0];
    }
  };

  issue(0);
  #pragma unroll 4
  for (int kt = 0; kt < KT; ++kt) {
    if constexpr (A16) {
      #pragma unroll
      for (int m = 0; m < 4; m++) { ah[m] = sah[m]; al[m] = sal[m]; }
    } else {
      #pragma unroll
      for (int m = 0; m < 4; m++) {
        float v[8] = {af[m][0].x, af[m][0].y, af[m][0].z, af[m][0].w,
                      af[m][1].x, af[m][1].y, af[m][1].z, af[m][1].w};
        #pragma unroll
        for (int j = 0; j < 8; j++) {
          __bf16 hh = (__bf16)v[j];
          ah[m][j] = hh;
          al[m][j] = (__bf16)(v[j] - (float)hh);
        }
      }
    }
    #pragma unroll
    for (int n = 0; n < 4; n++) { bh[n] = sbh[n]; bl[n] = sbl[n]; }
    if (kt + 1 < KT) issue(kt + 1);  // loads in flight under MFMA
    #pragma unroll
    for (int n = 0; n < 4; n++)
      #pragma unroll
      for (int m = 0; m < 4; m++) {
        acc[m][n] = __builtin_amdgcn_mfma_f32_16x16x32_bf16(ah[m], bh[n], acc[m][n], 0, 0, 0);
        acc[m][n] = __builtin_amdgcn_mfma_f32_16x16x32_bf16(al[m], bh[n], acc[m][n], 0, 0, 0);
        acc[m][n] = __builtin_amdgcn_mfma_f32_16x16x32_bf16(ah[m], bl[n], acc[m][n], 0, 0, 0);
      }
  }

  // epilogue: col = wc*64+n*16+(lane&15), row = r0+wr*64+m*16+4*(lane>>4)+j
  #pragma unroll
  for (int n = 0; n < 4; n++) {
    int col = wc * 64 + n * 16 + lr;
    float bc = bias[col];
    #pragma unroll
    for (int m = 0; m < 4; m++) {
      int rowb = r0 + wr * 64 + m * 16 + kg * 4;
      #pragma unroll
      for (int j = 0; j < 4; j++) {
        int row = rowb + j;
        if (row < N_NODES) {
          float v = acc[m][n][j] + bc;
          if (RELU) v = v > 0.f ? v : v * NEG_SLOPE;
          long o = (long)row * 128 + col;
          if (WF32) Cf[o] = v;
          if (WSPLIT) {
            __bf16 hh = (__bf16)v;
            Ch[o] = hh;
            Cl[o] = (__bf16)(v - (float)hh);
          }
          if (WF16) C16[o] = (_Float16)v;
        }
      }
    }
  }
}

// ---------------- mean aggregation (fp16 gather, bf16 hi/lo output) ----------------
__global__ __launch_bounds__(256) void k_agg(const _Float16* __restrict__ h16,
                                             const int* __restrict__ row_start,
                                             const int* __restrict__ csr_src,
                                             const float* __restrict__ inv_deg,
                                             __bf16* __restrict__ hn_h,
                                             __bf16* __restrict__ hn_l) {
  int node = blockIdx.x * 16 + (threadIdx.x >> 4);
  int lane = threadIdx.x & 15;
  int s = row_start[node];
  int e = row_start[node + 1];
  float acc[8];
  #pragma unroll
  for (int j = 0; j < 8; j++) acc[j] = 0.f;

  int i = s;
  for (; i + 4 <= e; i += 4) {
    int s0 = csr_src[i + 0];
    int s1 = csr_src[i + 1];
    int s2 = csr_src[i + 2];
    int s3 = csr_src[i + 3];
    half8 v0 = *(const half8*)&h16[(long)s0 * HIDDEN + lane * 8];
    half8 v1 = *(const half8*)&h16[(long)s1 * HIDDEN + lane * 8];
    half8 v2 = *(const half8*)&h16[(long)s2 * HIDDEN + lane * 8];
    half8 v3 = *(const half8*)&h16[(long)s3 * HIDDEN + lane * 8];
    #pragma unroll
    for (int j = 0; j < 8; j++)
      acc[j] += ((float)v0[j] + (float)v1[j]) + ((float)v2[j] + (float)v3[j]);
  }
  for (; i < e; ++i) {
    int sn = csr_src[i];
    half8 v = *(const half8*)&h16[(long)sn * HIDDEN + lane * 8];
    #pragma unroll
    for (int j = 0; j < 8; j++) acc[j] += (float)v[j];
  }

  float id = inv_deg[node];
  bf16x8 oh, ol;
  #pragma unroll
  for (int j = 0; j < 8; j++) {
    float v = acc[j] * id;
    __bf16 hh = (__bf16)v;
    oh[j] = hh;
    ol[j] = (__bf16)(v - (float)hh);
  }
  *(bf16x8*)&hn_h[(long)node * HIDDEN + lane * 8] = oh;
  *(bf16x8*)&hn_l[(long)node * HIDDEN + lane * 8] = ol;
}

// ---------------- output head ----------------
__global__ __launch_bounds__(256) void k_out(const float* __restrict__ h,
                                             const float* __restrict__ W_out,
                                             const float* __restrict__ b_out,
                                             float* __restrict__ out) {
  int node = blockIdx.x * 4 + (threadIdx.x >> 6);
  int l = threadIdx.x & 63;
  float a = h[node * HIDDEN + l];
  float b = h[node * HIDDEN + 64 + l];
  float s0 = a * W_out[l] + b * W_out[64 + l];
  float s1 = a * W_out[128 + l] + b * W_out[192 + l];
  #pragma unroll
  for (int d = 32; d >= 1; d >>= 1) {
    s0 += __shfl_xor(s0, d, 64);
    s1 += __shfl_xor(s1, d, 64);
  }
  if (l == 0) {
    out[node * 2 + 0] = s0 + b_out[0];
    out[node * 2 + 1] = s1 + b_out[1];
  }
}

extern "C" void kernel_launch(void* const* d_in, const int* in_sizes, int n_in,
                              void* d_out, int out_size, void* d_ws, size_t ws_size,
                              hipStream_t stream) {
  const float* features = (const float*)d_in[0];
  const int* src = (const int*)d_in[1];
  const int* dst = (const int*)d_in[2];
  const float* W_in = (const float*)d_in[3];
  const float* b_in = (const float*)d_in[4];
  const float* W_self = (const float*)d_in[5];
  const float* b_self = (const float*)d_in[6];
  const float* W_neigh = (const float*)d_in[7];
  const float* W_out = (const float*)d_in[8];
  const float* b_out = (const float*)d_in[9];
  float* out = (float*)d_out;

  char* ws = (char*)d_ws;
  float* h = (float*)(ws + 0);
  _Float16* h16 = (_Float16*)(ws + 51200000);
  __bf16* h_hi = (__bf16*)(ws + 76800000);
  __bf16* h_lo = (__bf16*)(ws + 102400000);
  __bf16* hn_h = (__bf16*)(ws + 128000000);
  __bf16* hn_l = (__bf16*)(ws + 153600000);
  int* deg = (int*)(ws + 179200000);
  float* inv_deg = (float*)(ws + 179600000);
  int* row_start = (int*)(ws + 180000000);
  int* cursor = (int*)(ws + 180400016);
  int* csr_src = (int*)(ws + 180800016);
  int* bsums = (int*)(ws + 187200016);
  int* boffs = (int*)(ws + 187200272);
  __bf16* W_in_h = (__bf16*)(ws + 187201024);
  __bf16* W_in_l = (__bf16*)(ws + 187332096);
  __bf16* W_sf_h = (__bf16*)(ws + 187463168);
  __bf16* W_sf_l = (__bf16*)(ws + 187528704);
  __bf16* W_ng_h = (__bf16*)(ws + 187594240);
  __bf16* W_ng_l = (__bf16*)(ws + 187659776);

  hipMemsetAsync(deg, 0, N_NODES * sizeof(int), stream);
  k_degree<<<N_RANGES * FILL_CHUNKS, 256, 0, stream>>>(dst, deg);
  k_scanA<<<SCAN_BLOCKS, 256, 0, stream>>>(deg, row_start, bsums);
  k_scanB<<<1, 64, 0, stream>>>(bsums, boffs);
  k_scanC<<<SCAN_BLOCKS, 256, 0, stream>>>(deg, row_start, cursor, inv_deg, boffs);
  k_fill<<<N_RANGES * FILL_CHUNKS, 256, 0, stream>>>(src, dst, cursor, csr_src);

  // weight pre-split (tiny)
  k_split<<<64, 256, 0, stream>>>(W_in, W_in_h, W_in_l, IN_FEATS * HIDDEN);
  k_split<<<32, 256, 0, stream>>>(W_self, W_sf_h, W_sf_l, 2 * HIDDEN * HIDDEN);
  k_split<<<32, 256, 0, stream>>>(W_neigh, W_ng_h, W_ng_l, 2 * HIDDEN * HIDDEN);

  // input projection: fp32 A, outputs h_hi/h_lo + h16
  k_gemm<IN_FEATS, 0, false, false, false, true, true><<<782, 256, 0, stream>>>(
      features, nullptr, nullptr, nullptr, W_in_h, W_in_l, nullptr, nullptr,
      b_in, nullptr, h_hi, h_lo, h16);

  // layer 0: bf16 A (h + hn), outputs h_hi/h_lo + h16 (in-place rows are block-local)
  k_agg<<<6250, 256, 0, stream>>>(h16, row_start, csr_src, inv_deg, hn_h, hn_l);
  k_gemm<HIDDEN, HIDDEN, true, true, false, true, true><<<782, 256, 0, stream>>>(
      h_hi, h_lo, hn_h, hn_l, W_sf_h, W_sf_l, W_ng_h, W_ng_l,
      b_self, nullptr, h_hi, h_lo, h16);

  // layer 1: outputs fp32 h only (feeds k_out)
  k_agg<<<6250, 256, 0, stream>>>(h16, row_start, csr_src, inv_deg, hn_h, hn_l);
  k_gemm<HIDDEN, HIDDEN, true, true, true, false, false><<<782, 256, 0, stream>>>(
      h_hi, h_lo, hn_h, hn_l, W_sf_h + HIDDEN * HIDDEN, W_sf_l + HIDDEN * HIDDEN,
      W_ng_h + HIDDEN * HIDDEN, W_ng_l + HIDDEN * HIDDEN,
      b_self + HIDDEN, h, nullptr, nullptr, nullptr);

  k_out<<<25000, 256, 0, stream>>>(h, W_out, b_out, out);
}